// Round 3
// baseline (1526.016 us; speedup 1.0000x reference)
//
#include <hip/hip_runtime.h>
#include <math.h>

#define CHN 128
#define TT 16384
#define NBATCH 8
#define KCONST 196608      // 128*128*3*4
#define TILE_T 64
#define GUARD 8
#define CRANGE 96          // computed range per layer: [T0-16, T0+80)
#define ROWS 112           // CRANGE + 2*GUARD, t = T0 - 24 + row
#define LROW 128           // ushorts per LDS row (256 B); 16B chunks XOR-swizzled

typedef __bf16 bf16x8 __attribute__((ext_vector_type(8)));
typedef float  f32x4  __attribute__((ext_vector_type(4)));
typedef unsigned short u16x8 __attribute__((ext_vector_type(8)));
typedef unsigned short u16x4 __attribute__((ext_vector_type(4)));

__device__ __forceinline__ unsigned short f2bf(float f) {
    union { float f; unsigned int u; } v; v.f = f;
    unsigned int u = v.u;
    u += 0x7fffu + ((u >> 16) & 1u);   // round-to-nearest-even
    return (unsigned short)(u >> 16);
}
__device__ __forceinline__ float b2f(unsigned short h) {
    union { float f; unsigned int u; } v; v.u = ((unsigned int)h) << 16;
    return v.f;
}

__device__ __forceinline__ float gelu_exact(float x) {
    return 0.5f * x * (1.0f + erff(x * 0.70710678118654752f));
}

// ------------- Kernel 1a: conv0 (80->64, k=5, pad=2) + gelu -> h0 -------------
__global__ __launch_bounds__(256) void k_cond0(
    const float* __restrict__ cond, const float* __restrict__ w0,
    const float* __restrict__ b0, float* __restrict__ h0)
{
    __shared__ float cS[80 * 32];
    __shared__ float wS[8 * 80 * 5];
    __shared__ float bS[8];
    int b = blockIdx.x >> 3, g = blockIdx.x & 7;
    int tid = threadIdx.x;

    for (int idx = tid; idx < 80 * 32; idx += 256) cS[idx] = cond[b * 2560 + idx];
    for (int idx = tid; idx < 8 * 400; idx += 256) wS[idx] = w0[g * 3200 + idx];
    if (tid < 8) bS[tid] = b0[g * 8 + tid];
    __syncthreads();

    int oc = tid >> 5, t = tid & 31;
    float acc = bS[oc];
    const float* wr = wS + oc * 400;
    for (int ic = 0; ic < 80; ++ic) {
        const float* cr = cS + ic * 32;
        #pragma unroll
        for (int j = 0; j < 5; ++j) {
            int tv = t - 2 + j;
            if (tv >= 0 && tv < 32) acc += wr[ic * 5 + j] * cr[tv];
        }
    }
    h0[(b * 64 + g * 8 + oc) * 32 + t] = gelu_exact(acc);
}

// ------ Kernel 1b: conv1 (64->64, k=3, pad=1) + gelu + mean_t -> hbar --------
__global__ __launch_bounds__(256) void k_cond1(
    const float* __restrict__ h0, const float* __restrict__ w1,
    const float* __restrict__ b1, float* __restrict__ hbar)
{
    __shared__ float hS[64 * 32];
    __shared__ float wS[8 * 64 * 3];
    __shared__ float bS[8];
    int b = blockIdx.x >> 3, g = blockIdx.x & 7;
    int tid = threadIdx.x;

    for (int idx = tid; idx < 64 * 32; idx += 256) hS[idx] = h0[b * 2048 + idx];
    for (int idx = tid; idx < 8 * 192; idx += 256) wS[idx] = w1[g * 1536 + idx];
    if (tid < 8) bS[tid] = b1[g * 8 + tid];
    __syncthreads();

    int oc = tid >> 5, t = tid & 31;
    float acc = bS[oc];
    const float* wr = wS + oc * 192;
    for (int ic = 0; ic < 64; ++ic) {
        const float* hr = hS + ic * 32;
        #pragma unroll
        for (int j = 0; j < 3; ++j) {
            int tv = t - 1 + j;
            if (tv >= 0 && tv < 32) acc += wr[ic * 3 + j] * hr[tv];
        }
    }
    float v = gelu_exact(acc);
    #pragma unroll
    for (int off = 1; off < 32; off <<= 1) v += __shfl_xor(v, off, 64);
    if (t == 0) hbar[b * 64 + g * 8 + oc] = v * (1.0f / 32.0f);
}

// ---- Kernel 2: kernels/biases. LDS-staged coalesced w2 reads. ----
__global__ __launch_bounds__(256) void k_weights(
    const float* __restrict__ w2, const float* __restrict__ b2,
    const float* __restrict__ hbar,
    unsigned short* __restrict__ W, float* __restrict__ bmean)
{
    __shared__ float hS[8 * 64];
    __shared__ float buf[256 * 68];   // 256 rows x 64 floats, +4 pad
    int tid = threadIdx.x;
    for (int idx = tid; idx < 512; idx += 256) hS[idx] = hbar[idx];

    // stage this block's 256 w2 rows (64 KB) via coalesced float4 stream
    const float4* src4 = (const float4*)(w2 + (long)blockIdx.x * 16384);
    #pragma unroll
    for (int it = 0; it < 16; ++it) {
        int f = it * 256 + tid;
        float4 v = src4[f];
        int row = f >> 4, col = f & 15;
        *(float4*)&buf[row * 68 + col * 4] = v;
    }
    __syncthreads();

    long p = (long)blockIdx.x * 256 + tid;   // [0, 197632), exact
    const float* rowp = &buf[tid * 68];
    float acc[8];
    #pragma unroll
    for (int bb = 0; bb < 8; ++bb) acc[bb] = 0.f;
    #pragma unroll
    for (int q = 0; q < 16; ++q) {
        float4 wv = *(const float4*)&rowp[q * 4];
        #pragma unroll
        for (int bb = 0; bb < 8; ++bb) {
            const float* h = hS + bb * 64 + q * 4;
            acc[bb] += wv.x * h[0] + wv.y * h[1] + wv.z * h[2] + wv.w * h[3];
        }
    }
    float bias = b2[p];
    if (p < KCONST) {
        int i = (int)(p / 49152); int r = (int)(p % 49152);
        int o = r / 384; int m = r % 384; int c = m / 3; int tp = m % 3;
        #pragma unroll
        for (int bb = 0; bb < 8; ++bb)
            W[(long)((bb * 4 + i) * 128 + o) * 384 + tp * 128 + c] =
                f2bf(acc[bb] + bias);
    } else {
        int q = (int)(p - KCONST); int i = q >> 7, o = q & 127;
        #pragma unroll
        for (int bb = 0; bb < 8; ++bb)
            bmean[(bb * 4 + i) * 128 + o] = acc[bb] + bias;
    }
}

// ------ Kernel 3: ALL 4 dilated conv layers fused, signal lives in LDS ------
// v4: (a) 2x2 wave split: wave=(wm,wn) owns o in [wm*64,+64) x 48 t-rows ->
//     each B-frag read by 2 waves (was 4), block LDS B-traffic halves;
// (b) A-frags + bias for layer l+1 prefetched into regs (af[12][4], 192 VGPR)
//     between the writeback and the closing barrier -> L2 latency drains
//     while waves wait; layer-0 A overlaps x-staging. (256,3) gives ~680
//     unified regs/wave headroom so no spill (watch WRITE_SIZE).
// (c) LROW=128 (no pad) + XOR swizzle of 16B chunks (chunk ^= row&7) applied
//     at staging, writeback, and B-read -> conflict-free-by-construction.
// fp32 residual chain lives in the MFMA accumulator (C-in carries x_l, never
// re-zeroed); acc initialized from x while staged lines are cache-hot.
// All layers compute rows 8..104 = [T0-16,T0+80); stale guard rows only
// corrupt edge outputs discarded by validity analysis (valid y3 superset
// [T0-2,T0+66) superset of stored [T0,T0+64)).
__global__ __launch_bounds__(256, 3) void k_fused(
    const float* __restrict__ src, float* __restrict__ dst,
    const unsigned short* __restrict__ W, const float* __restrict__ bmean,
    const float* __restrict__ alpha)
{
    __shared__ __align__(16) unsigned short xhi[ROWS * LROW];  // 28672 B

    int tid  = threadIdx.x;
    int lane = tid & 63;
    int wave = tid >> 6;
    int b    = blockIdx.x >> 8;
    int tile = blockIdx.x & 255;
    int T0   = tile * TILE_T;

    int nrow = lane & 15;
    int quad = lane >> 4;
    int wm   = wave & 1;          // o-half
    int wn   = wave >> 1;         // t-half
    int o0   = wm * 64;
    int tb   = wn * 48;           // row offset within the 96 computed rows

    const float* xb = src + (long)b * CHN * TT;

    bf16x8 af[12][4];
    float  bias[4][4];

    auto loadA = [&](int l) {
        const unsigned short* Wl = W + (long)((b * 4 + l) * 128) * 384;
        const float* bm = bmean + (b * 4 + l) * 128;
        #pragma unroll
        for (int ks = 0; ks < 12; ++ks) {
            const unsigned short* wr =
                Wl + (long)(o0 + nrow) * 384 + ks * 32 + quad * 8;
            #pragma unroll
            for (int m = 0; m < 4; ++m)
                af[ks][m] = *(const bf16x8*)(wr + m * 16 * 384);
        }
        #pragma unroll
        for (int m = 0; m < 4; ++m) {
            int obase = o0 + m * 16 + quad * 4;
            #pragma unroll
            for (int r = 0; r < 4; ++r) bias[m][r] = bm[obase + r];
        }
    };

    loadA(0);   // in flight under the staging loads below

    // --- stage x (bf16 hi) into the swizzled LDS image ---
    {
        int cb   = wave * 32;
        int c16b = wave * 4;      // chunk base = cb/8
        #pragma unroll 1
        for (int pass = 0; pass < 2; ++pass) {
            int tl = pass * 64 + lane;
            if (tl < ROWS) {
                int tg = T0 - 24 + tl;
                bool ok = (tg >= 0) && (tg < TT);
                int sw = tl & 7;
                #pragma unroll
                for (int kb = 0; kb < 4; ++kb) {
                    float v[8];
                    #pragma unroll
                    for (int k = 0; k < 8; ++k)
                        v[k] = ok ? xb[(long)(cb + kb * 8 + k) * TT + tg] : 0.f;
                    u16x8 h;
                    #pragma unroll
                    for (int k = 0; k < 8; ++k) h[k] = f2bf(v[k]);
                    *(u16x8*)&xhi[tl * LROW + (((c16b + kb) ^ sw) << 3)] = h;
                }
            }
        }
    }

    // persistent fp32 accumulator = residual chain; init acc = x (cache-hot)
    f32x4 acc[4][3];
    #pragma unroll
    for (int m = 0; m < 4; ++m) {
        int obase = o0 + m * 16 + quad * 4;
        #pragma unroll
        for (int nt = 0; nt < 3; ++nt) {
            int tg = T0 - 16 + tb + nt * 16 + nrow;
            bool ok = ((unsigned)tg < (unsigned)TT);
            #pragma unroll
            for (int r = 0; r < 4; ++r)
                acc[m][nt][r] = ok ? xb[(long)(obase + r) * TT + tg] : 0.f;
        }
    }

    __syncthreads();

    #pragma unroll 1
    for (int l = 0; l < 4; ++l) {
        const int d = 1 << l;

        // K-loop: pure LDS + MFMA (A already in regs); B-frag feeds 4 m-tiles
        #pragma unroll
        for (int ks = 0; ks < 12; ++ks) {
            int roff = GUARD + tb + nrow + ((ks >> 2) - 1) * d;
            int ch   = (((ks & 3) * 4 + quad) ^ (roff & 7)) << 3;
            #pragma unroll
            for (int nt = 0; nt < 3; ++nt) {
                bf16x8 bf =
                    *(const bf16x8*)&xhi[(roff + nt * 16) * LROW + ch];
                acc[0][nt] = __builtin_amdgcn_mfma_f32_16x16x32_bf16(
                    af[ks][0], bf, acc[0][nt], 0, 0, 0);
                acc[1][nt] = __builtin_amdgcn_mfma_f32_16x16x32_bf16(
                    af[ks][1], bf, acc[1][nt], 0, 0, 0);
                acc[2][nt] = __builtin_amdgcn_mfma_f32_16x16x32_bf16(
                    af[ks][2], bf, acc[2][nt], 0, 0, 0);
                acc[3][nt] = __builtin_amdgcn_mfma_f32_16x16x32_bf16(
                    af[ks][3], bf, acc[3][nt], 0, 0, 0);
            }
        }

        // fold bias into acc (residual already carried in acc)
        #pragma unroll
        for (int m = 0; m < 4; ++m)
            #pragma unroll
            for (int nt = 0; nt < 3; ++nt)
                #pragma unroll
                for (int r = 0; r < 4; ++r)
                    acc[m][nt][r] += bias[m][r];

        __syncthreads();   // all LDS reads of layer l done before any write

        if (l < 3) {
            // write back the bf16 image for layer l+1 (swizzled)
            #pragma unroll
            for (int m = 0; m < 4; ++m) {
                int obase = o0 + m * 16 + quad * 4;
                int ch0 = obase >> 3, sub = obase & 7;
                #pragma unroll
                for (int nt = 0; nt < 3; ++nt) {
                    int trow = GUARD + tb + nt * 16 + nrow;
                    int tg = T0 - 16 + tb + nt * 16 + nrow;
                    bool ok = ((unsigned)tg < (unsigned)TT);
                    u16x4 h;
                    #pragma unroll
                    for (int r = 0; r < 4; ++r) {
                        float v = ok ? acc[m][nt][r] : 0.f;
                        h[r] = f2bf(v);
                    }
                    *(u16x4*)&xhi[trow * LROW +
                                  (((ch0 ^ (trow & 7)) << 3) + sub)] = h;
                }
            }
            loadA(l + 1);      // A/bias of next layer in flight across barrier
            __syncthreads();
        } else {
            // final layer: sin activation, store only the valid 64-t core
            #pragma unroll
            for (int m = 0; m < 4; ++m) {
                #pragma unroll
                for (int r = 0; r < 4; ++r) {
                    int o = o0 + m * 16 + quad * 4 + r;
                    float av = alpha[o];
                    float rcp = 1.0f / (av + 1e-8f);
                    long rowoff = ((long)b * CHN + o) * TT + T0;
                    #pragma unroll
                    for (int nt = 0; nt < 3; ++nt) {
                        int trel0 = tb + nt * 16 - 16;
                        if ((unsigned)trel0 < 64u) {   // wave-uniform guard
                            float xn = acc[m][nt][r];
                            float s = __sinf(av * xn);
                            dst[rowoff + trel0 + nrow] = xn + rcp * s * s;
                        }
                    }
                }
            }
        }
    }
}

extern "C" void kernel_launch(void* const* d_in, const int* in_sizes, int n_in,
                              void* d_out, int out_size, void* d_ws, size_t ws_size,
                              hipStream_t stream) {
    const float* x     = (const float*)d_in[0];
    const float* cond  = (const float*)d_in[1];
    const float* w0    = (const float*)d_in[2];
    const float* b0    = (const float*)d_in[3];
    const float* w1    = (const float*)d_in[4];
    const float* b1    = (const float*)d_in[5];
    const float* w2    = (const float*)d_in[6];
    const float* b2    = (const float*)d_in[7];
    const float* alpha = (const float*)d_in[8];
    float* out = (float*)d_out;

    char* ws = (char*)d_ws;
    unsigned short* W = (unsigned short*)ws;               // 3,145,728 B
    float* bmean = (float*)(ws + 3145728);                 // 16,384 B
    float* hbar  = (float*)(ws + 3162112);                 // 2,048 B
    float* h0    = (float*)(ws + 3164160);                 // 65,536 B

    k_cond0<<<64, 256, 0, stream>>>(cond, w0, b0, h0);
    k_cond1<<<64, 256, 0, stream>>>(h0, w1, b1, hbar);
    k_weights<<<772, 256, 0, stream>>>(w2, b2, hbar, W, bmean);
    k_fused<<<2048, 256, 0, stream>>>(x, out, W, bmean, alpha);
}

// Round 4
// 412.002 us; speedup vs baseline: 3.7039x; 3.7039x over previous
//
#include <hip/hip_runtime.h>
#include <math.h>

#define CHN 128
#define TT 16384
#define NBATCH 8
#define KCONST 196608      // 128*128*3*4
#define TILE_T 64
#define GUARD 8
#define CRANGE 96          // computed range per layer: [T0-16, T0+80)
#define ROWS 112           // CRANGE + 2*GUARD, t = T0 - 24 + row
#define LROW 128           // ushorts per LDS row (256 B); 16B chunks XOR-swizzled

typedef __bf16 bf16x8 __attribute__((ext_vector_type(8)));
typedef float  f32x4  __attribute__((ext_vector_type(4)));
typedef unsigned short u16x8 __attribute__((ext_vector_type(8)));
typedef unsigned short u16x4 __attribute__((ext_vector_type(4)));

__device__ __forceinline__ unsigned short f2bf(float f) {
    union { float f; unsigned int u; } v; v.f = f;
    unsigned int u = v.u;
    u += 0x7fffu + ((u >> 16) & 1u);   // round-to-nearest-even
    return (unsigned short)(u >> 16);
}
__device__ __forceinline__ float b2f(unsigned short h) {
    union { float f; unsigned int u; } v; v.u = ((unsigned int)h) << 16;
    return v.f;
}

__device__ __forceinline__ float gelu_exact(float x) {
    return 0.5f * x * (1.0f + erff(x * 0.70710678118654752f));
}

// ------------- Kernel 1a: conv0 (80->64, k=5, pad=2) + gelu -> h0 -------------
__global__ __launch_bounds__(256) void k_cond0(
    const float* __restrict__ cond, const float* __restrict__ w0,
    const float* __restrict__ b0, float* __restrict__ h0)
{
    __shared__ float cS[80 * 32];
    __shared__ float wS[8 * 80 * 5];
    __shared__ float bS[8];
    int b = blockIdx.x >> 3, g = blockIdx.x & 7;
    int tid = threadIdx.x;

    for (int idx = tid; idx < 80 * 32; idx += 256) cS[idx] = cond[b * 2560 + idx];
    for (int idx = tid; idx < 8 * 400; idx += 256) wS[idx] = w0[g * 3200 + idx];
    if (tid < 8) bS[tid] = b0[g * 8 + tid];
    __syncthreads();

    int oc = tid >> 5, t = tid & 31;
    float acc = bS[oc];
    const float* wr = wS + oc * 400;
    for (int ic = 0; ic < 80; ++ic) {
        const float* cr = cS + ic * 32;
        #pragma unroll
        for (int j = 0; j < 5; ++j) {
            int tv = t - 2 + j;
            if (tv >= 0 && tv < 32) acc += wr[ic * 5 + j] * cr[tv];
        }
    }
    h0[(b * 64 + g * 8 + oc) * 32 + t] = gelu_exact(acc);
}

// ------ Kernel 1b: conv1 (64->64, k=3, pad=1) + gelu + mean_t -> hbar --------
__global__ __launch_bounds__(256) void k_cond1(
    const float* __restrict__ h0, const float* __restrict__ w1,
    const float* __restrict__ b1, float* __restrict__ hbar)
{
    __shared__ float hS[64 * 32];
    __shared__ float wS[8 * 64 * 3];
    __shared__ float bS[8];
    int b = blockIdx.x >> 3, g = blockIdx.x & 7;
    int tid = threadIdx.x;

    for (int idx = tid; idx < 64 * 32; idx += 256) hS[idx] = h0[b * 2048 + idx];
    for (int idx = tid; idx < 8 * 192; idx += 256) wS[idx] = w1[g * 1536 + idx];
    if (tid < 8) bS[tid] = b1[g * 8 + tid];
    __syncthreads();

    int oc = tid >> 5, t = tid & 31;
    float acc = bS[oc];
    const float* wr = wS + oc * 192;
    for (int ic = 0; ic < 64; ++ic) {
        const float* hr = hS + ic * 32;
        #pragma unroll
        for (int j = 0; j < 3; ++j) {
            int tv = t - 1 + j;
            if (tv >= 0 && tv < 32) acc += wr[ic * 3 + j] * hr[tv];
        }
    }
    float v = gelu_exact(acc);
    #pragma unroll
    for (int off = 1; off < 32; off <<= 1) v += __shfl_xor(v, off, 64);
    if (t == 0) hbar[b * 64 + g * 8 + oc] = v * (1.0f / 32.0f);
}

// ---- Kernel 2: kernels/biases. LDS-staged coalesced w2 reads. ----
__global__ __launch_bounds__(256) void k_weights(
    const float* __restrict__ w2, const float* __restrict__ b2,
    const float* __restrict__ hbar,
    unsigned short* __restrict__ W, float* __restrict__ bmean)
{
    __shared__ float hS[8 * 64];
    __shared__ float buf[256 * 68];   // 256 rows x 64 floats, +4 pad
    int tid = threadIdx.x;
    for (int idx = tid; idx < 512; idx += 256) hS[idx] = hbar[idx];

    // stage this block's 256 w2 rows (64 KB) via coalesced float4 stream
    const float4* src4 = (const float4*)(w2 + (long)blockIdx.x * 16384);
    #pragma unroll
    for (int it = 0; it < 16; ++it) {
        int f = it * 256 + tid;
        float4 v = src4[f];
        int row = f >> 4, col = f & 15;
        *(float4*)&buf[row * 68 + col * 4] = v;
    }
    __syncthreads();

    long p = (long)blockIdx.x * 256 + tid;   // [0, 197632), exact
    const float* rowp = &buf[tid * 68];
    float acc[8];
    #pragma unroll
    for (int bb = 0; bb < 8; ++bb) acc[bb] = 0.f;
    #pragma unroll
    for (int q = 0; q < 16; ++q) {
        float4 wv = *(const float4*)&rowp[q * 4];
        #pragma unroll
        for (int bb = 0; bb < 8; ++bb) {
            const float* h = hS + bb * 64 + q * 4;
            acc[bb] += wv.x * h[0] + wv.y * h[1] + wv.z * h[2] + wv.w * h[3];
        }
    }
    float bias = b2[p];
    if (p < KCONST) {
        int i = (int)(p / 49152); int r = (int)(p % 49152);
        int o = r / 384; int m = r % 384; int c = m / 3; int tp = m % 3;
        #pragma unroll
        for (int bb = 0; bb < 8; ++bb)
            W[(long)((bb * 4 + i) * 128 + o) * 384 + tp * 128 + c] =
                f2bf(acc[bb] + bias);
    } else {
        int q = (int)(p - KCONST); int i = q >> 7, o = q & 127;
        #pragma unroll
        for (int bb = 0; bb < 8; ++bb)
            bmean[(bb * 4 + i) * 128 + o] = acc[bb] + bias;
    }
}

// ------ Kernel 3: ALL 4 dilated conv layers fused, signal lives in LDS ------
// v5 = v3's register discipline + v4's verified wave split & swizzle:
// (a) 2x2 wave split: wave=(wm,wn) owns o in [wm*64,+64) x 48 t-rows -> each
//     B-frag feeds 4 m-tiles and is read by only 2 waves (block LDS B-traffic
//     halved vs v3);
// (b) LROW=128 (no pad) + XOR swizzle of 16B chunks (chunk ^= row&7) at
//     staging, writeback, and B-read -> bank-uniform b128 reads and u16x4
//     writebacks (v4-verified logic);
// (c) A-frags loaded PER-KS inside the K-loop (4 transient frags, ~16 regs) --
//     v3's proven pattern. NO full-layer register prefetch: round-3 showed
//     af[12][4] (192 regs) exceeds the ~170 unified VGPR+AGPR cap of
//     __launch_bounds__(256,3) and goes to scratch (3.4 GB of spill traffic).
// fp32 residual chain lives in the MFMA accumulator (C-in carries x_l, never
// re-zeroed); acc initialized from x while staged lines are cache-hot.
// All layers compute rows 8..104 = [T0-16,T0+80); stale guard rows only
// corrupt edge outputs discarded by validity analysis (valid y3 superset
// [T0-2,T0+66) superset of stored [T0,T0+64)).
__global__ __launch_bounds__(256, 3) void k_fused(
    const float* __restrict__ src, float* __restrict__ dst,
    const unsigned short* __restrict__ W, const float* __restrict__ bmean,
    const float* __restrict__ alpha)
{
    __shared__ __align__(16) unsigned short xhi[ROWS * LROW];  // 28672 B

    int tid  = threadIdx.x;
    int lane = tid & 63;
    int wave = tid >> 6;
    int b    = blockIdx.x >> 8;
    int tile = blockIdx.x & 255;
    int T0   = tile * TILE_T;

    int nrow = lane & 15;
    int quad = lane >> 4;
    int wm   = wave & 1;          // o-half
    int wn   = wave >> 1;         // t-half
    int o0   = wm * 64;
    int tb   = wn * 48;           // row offset within the 96 computed rows

    const float* xb = src + (long)b * CHN * TT;

    // --- stage x (bf16 hi) into the swizzled LDS image ---
    {
        int cb   = wave * 32;
        int c16b = wave * 4;      // chunk base = cb/8
        #pragma unroll 1
        for (int pass = 0; pass < 2; ++pass) {
            int tl = pass * 64 + lane;
            if (tl < ROWS) {
                int tg = T0 - 24 + tl;
                bool ok = (tg >= 0) && (tg < TT);
                int sw = tl & 7;
                #pragma unroll
                for (int kb = 0; kb < 4; ++kb) {
                    float v[8];
                    #pragma unroll
                    for (int k = 0; k < 8; ++k)
                        v[k] = ok ? xb[(long)(cb + kb * 8 + k) * TT + tg] : 0.f;
                    u16x8 h;
                    #pragma unroll
                    for (int k = 0; k < 8; ++k) h[k] = f2bf(v[k]);
                    *(u16x8*)&xhi[tl * LROW + (((c16b + kb) ^ sw) << 3)] = h;
                }
            }
        }
    }

    // persistent fp32 accumulator = residual chain; init acc = x (cache-hot)
    f32x4 acc[4][3];
    #pragma unroll
    for (int m = 0; m < 4; ++m) {
        int obase = o0 + m * 16 + quad * 4;
        #pragma unroll
        for (int nt = 0; nt < 3; ++nt) {
            int tg = T0 - 16 + tb + nt * 16 + nrow;
            bool ok = ((unsigned)tg < (unsigned)TT);
            #pragma unroll
            for (int r = 0; r < 4; ++r)
                acc[m][nt][r] = ok ? xb[(long)(obase + r) * TT + tg] : 0.f;
        }
    }

    __syncthreads();

    #pragma unroll 1
    for (int l = 0; l < 4; ++l) {
        const int d = 1 << l;
        const unsigned short* Wl = W + (long)((b * 4 + l) * 128) * 384;
        const float* bm = bmean + (b * 4 + l) * 128;

        // bias for this layer (16 regs); loads drain under the K-loop
        float bias[4][4];
        #pragma unroll
        for (int m = 0; m < 4; ++m) {
            int obase = o0 + m * 16 + quad * 4;
            #pragma unroll
            for (int r = 0; r < 4; ++r) bias[m][r] = bm[obase + r];
        }

        // K-loop: per-ks A-loads (4 transient frags) + swizzled B ds_reads;
        // B-frag feeds 4 m-tiles; MFMA C-in carries x_l (fp32 residual)
        #pragma unroll
        for (int ks = 0; ks < 12; ++ks) {
            int roff = GUARD + tb + nrow + ((ks >> 2) - 1) * d;
            int ch   = (((ks & 3) * 4 + quad) ^ (roff & 7)) << 3;
            const unsigned short* wr =
                Wl + (long)(o0 + nrow) * 384 + ks * 32 + quad * 8;
            bf16x8 a0 = *(const bf16x8*)(wr);
            bf16x8 a1 = *(const bf16x8*)(wr + 16 * 384);
            bf16x8 a2 = *(const bf16x8*)(wr + 32 * 384);
            bf16x8 a3 = *(const bf16x8*)(wr + 48 * 384);
            #pragma unroll
            for (int nt = 0; nt < 3; ++nt) {
                bf16x8 bf =
                    *(const bf16x8*)&xhi[(roff + nt * 16) * LROW + ch];
                acc[0][nt] = __builtin_amdgcn_mfma_f32_16x16x32_bf16(
                    a0, bf, acc[0][nt], 0, 0, 0);
                acc[1][nt] = __builtin_amdgcn_mfma_f32_16x16x32_bf16(
                    a1, bf, acc[1][nt], 0, 0, 0);
                acc[2][nt] = __builtin_amdgcn_mfma_f32_16x16x32_bf16(
                    a2, bf, acc[2][nt], 0, 0, 0);
                acc[3][nt] = __builtin_amdgcn_mfma_f32_16x16x32_bf16(
                    a3, bf, acc[3][nt], 0, 0, 0);
            }
        }

        // fold bias into acc (residual already carried in acc)
        #pragma unroll
        for (int m = 0; m < 4; ++m)
            #pragma unroll
            for (int nt = 0; nt < 3; ++nt)
                #pragma unroll
                for (int r = 0; r < 4; ++r)
                    acc[m][nt][r] += bias[m][r];

        __syncthreads();   // all LDS reads of layer l done before any write

        if (l < 3) {
            // write back the bf16 image for layer l+1 (swizzled)
            #pragma unroll
            for (int m = 0; m < 4; ++m) {
                int obase = o0 + m * 16 + quad * 4;
                int ch0 = obase >> 3, sub = obase & 7;
                #pragma unroll
                for (int nt = 0; nt < 3; ++nt) {
                    int trow = GUARD + tb + nt * 16 + nrow;
                    int tg = T0 - 16 + tb + nt * 16 + nrow;
                    bool ok = ((unsigned)tg < (unsigned)TT);
                    u16x4 h;
                    #pragma unroll
                    for (int r = 0; r < 4; ++r) {
                        float v = ok ? acc[m][nt][r] : 0.f;
                        h[r] = f2bf(v);
                    }
                    *(u16x4*)&xhi[trow * LROW +
                                  (((ch0 ^ (trow & 7)) << 3) + sub)] = h;
                }
            }
            __syncthreads();
        } else {
            // final layer: sin activation, store only the valid 64-t core
            #pragma unroll
            for (int m = 0; m < 4; ++m) {
                #pragma unroll
                for (int r = 0; r < 4; ++r) {
                    int o = o0 + m * 16 + quad * 4 + r;
                    float av = alpha[o];
                    float rcp = 1.0f / (av + 1e-8f);
                    long rowoff = ((long)b * CHN + o) * TT + T0;
                    #pragma unroll
                    for (int nt = 0; nt < 3; ++nt) {
                        int trel0 = tb + nt * 16 - 16;
                        if ((unsigned)trel0 < 64u) {   // wave-uniform guard
                            float xn = acc[m][nt][r];
                            float s = __sinf(av * xn);
                            dst[rowoff + trel0 + nrow] = xn + rcp * s * s;
                        }
                    }
                }
            }
        }
    }
}

extern "C" void kernel_launch(void* const* d_in, const int* in_sizes, int n_in,
                              void* d_out, int out_size, void* d_ws, size_t ws_size,
                              hipStream_t stream) {
    const float* x     = (const float*)d_in[0];
    const float* cond  = (const float*)d_in[1];
    const float* w0    = (const float*)d_in[2];
    const float* b0    = (const float*)d_in[3];
    const float* w1    = (const float*)d_in[4];
    const float* b1    = (const float*)d_in[5];
    const float* w2    = (const float*)d_in[6];
    const float* b2    = (const float*)d_in[7];
    const float* alpha = (const float*)d_in[8];
    float* out = (float*)d_out;

    char* ws = (char*)d_ws;
    unsigned short* W = (unsigned short*)ws;               // 3,145,728 B
    float* bmean = (float*)(ws + 3145728);                 // 16,384 B
    float* hbar  = (float*)(ws + 3162112);                 // 2,048 B
    float* h0    = (float*)(ws + 3164160);                 // 65,536 B

    k_cond0<<<64, 256, 0, stream>>>(cond, w0, b0, h0);
    k_cond1<<<64, 256, 0, stream>>>(h0, w1, b1, hbar);
    k_weights<<<772, 256, 0, stream>>>(w2, b2, hbar, W, bmean);
    k_fused<<<2048, 256, 0, stream>>>(x, out, W, bmean, alpha);
}

// Round 5
// 411.331 us; speedup vs baseline: 3.7099x; 1.0016x over previous
//
#include <hip/hip_runtime.h>
#include <math.h>

#define CHN 128
#define TT 16384
#define NBATCH 8
#define KCONST 196608      // 128*128*3*4
#define TILE_T 64
#define GUARD 8
#define CRANGE 96          // computed range per layer: [T0-16, T0+80)
#define ROWS 112           // CRANGE + 2*GUARD, t = T0 - 24 + row
#define LROW 128           // ushorts per LDS row (256 B); 16B chunks XOR-swizzled

typedef __bf16 bf16x8 __attribute__((ext_vector_type(8)));
typedef float  f32x4  __attribute__((ext_vector_type(4)));
typedef unsigned short u16x8 __attribute__((ext_vector_type(8)));
typedef unsigned short u16x4 __attribute__((ext_vector_type(4)));

__device__ __forceinline__ unsigned short f2bf(float f) {
    union { float f; unsigned int u; } v; v.f = f;
    unsigned int u = v.u;
    u += 0x7fffu + ((u >> 16) & 1u);   // round-to-nearest-even
    return (unsigned short)(u >> 16);
}
__device__ __forceinline__ float b2f(unsigned short h) {
    union { float f; unsigned int u; } v; v.u = ((unsigned int)h) << 16;
    return v.f;
}

__device__ __forceinline__ float gelu_exact(float x) {
    return 0.5f * x * (1.0f + erff(x * 0.70710678118654752f));
}

// ------------- Kernel 1a: conv0 (80->64, k=5, pad=2) + gelu -> h0 -------------
__global__ __launch_bounds__(256) void k_cond0(
    const float* __restrict__ cond, const float* __restrict__ w0,
    const float* __restrict__ b0, float* __restrict__ h0)
{
    __shared__ float cS[80 * 32];
    __shared__ float wS[8 * 80 * 5];
    __shared__ float bS[8];
    int b = blockIdx.x >> 3, g = blockIdx.x & 7;
    int tid = threadIdx.x;

    for (int idx = tid; idx < 80 * 32; idx += 256) cS[idx] = cond[b * 2560 + idx];
    for (int idx = tid; idx < 8 * 400; idx += 256) wS[idx] = w0[g * 3200 + idx];
    if (tid < 8) bS[tid] = b0[g * 8 + tid];
    __syncthreads();

    int oc = tid >> 5, t = tid & 31;
    float acc = bS[oc];
    const float* wr = wS + oc * 400;
    for (int ic = 0; ic < 80; ++ic) {
        const float* cr = cS + ic * 32;
        #pragma unroll
        for (int j = 0; j < 5; ++j) {
            int tv = t - 2 + j;
            if (tv >= 0 && tv < 32) acc += wr[ic * 5 + j] * cr[tv];
        }
    }
    h0[(b * 64 + g * 8 + oc) * 32 + t] = gelu_exact(acc);
}

// ------ Kernel 1b: conv1 (64->64, k=3, pad=1) + gelu + mean_t -> hbar --------
__global__ __launch_bounds__(256) void k_cond1(
    const float* __restrict__ h0, const float* __restrict__ w1,
    const float* __restrict__ b1, float* __restrict__ hbar)
{
    __shared__ float hS[64 * 32];
    __shared__ float wS[8 * 64 * 3];
    __shared__ float bS[8];
    int b = blockIdx.x >> 3, g = blockIdx.x & 7;
    int tid = threadIdx.x;

    for (int idx = tid; idx < 64 * 32; idx += 256) hS[idx] = h0[b * 2048 + idx];
    for (int idx = tid; idx < 8 * 192; idx += 256) wS[idx] = w1[g * 1536 + idx];
    if (tid < 8) bS[tid] = b1[g * 8 + tid];
    __syncthreads();

    int oc = tid >> 5, t = tid & 31;
    float acc = bS[oc];
    const float* wr = wS + oc * 192;
    for (int ic = 0; ic < 64; ++ic) {
        const float* hr = hS + ic * 32;
        #pragma unroll
        for (int j = 0; j < 3; ++j) {
            int tv = t - 1 + j;
            if (tv >= 0 && tv < 32) acc += wr[ic * 3 + j] * hr[tv];
        }
    }
    float v = gelu_exact(acc);
    #pragma unroll
    for (int off = 1; off < 32; off <<= 1) v += __shfl_xor(v, off, 64);
    if (t == 0) hbar[b * 64 + g * 8 + oc] = v * (1.0f / 32.0f);
}

// ---- Kernel 2: kernels/biases. LDS-staged coalesced w2 reads. ----
__global__ __launch_bounds__(256) void k_weights(
    const float* __restrict__ w2, const float* __restrict__ b2,
    const float* __restrict__ hbar,
    unsigned short* __restrict__ W, float* __restrict__ bmean)
{
    __shared__ float hS[8 * 64];
    __shared__ float buf[256 * 68];   // 256 rows x 64 floats, +4 pad
    int tid = threadIdx.x;
    for (int idx = tid; idx < 512; idx += 256) hS[idx] = hbar[idx];

    // stage this block's 256 w2 rows (64 KB) via coalesced float4 stream
    const float4* src4 = (const float4*)(w2 + (long)blockIdx.x * 16384);
    #pragma unroll
    for (int it = 0; it < 16; ++it) {
        int f = it * 256 + tid;
        float4 v = src4[f];
        int row = f >> 4, col = f & 15;
        *(float4*)&buf[row * 68 + col * 4] = v;
    }
    __syncthreads();

    long p = (long)blockIdx.x * 256 + tid;   // [0, 197632), exact
    const float* rowp = &buf[tid * 68];
    float acc[8];
    #pragma unroll
    for (int bb = 0; bb < 8; ++bb) acc[bb] = 0.f;
    #pragma unroll
    for (int q = 0; q < 16; ++q) {
        float4 wv = *(const float4*)&rowp[q * 4];
        #pragma unroll
        for (int bb = 0; bb < 8; ++bb) {
            const float* h = hS + bb * 64 + q * 4;
            acc[bb] += wv.x * h[0] + wv.y * h[1] + wv.z * h[2] + wv.w * h[3];
        }
    }
    float bias = b2[p];
    if (p < KCONST) {
        int i = (int)(p / 49152); int r = (int)(p % 49152);
        int o = r / 384; int m = r % 384; int c = m / 3; int tp = m % 3;
        #pragma unroll
        for (int bb = 0; bb < 8; ++bb)
            W[(long)((bb * 4 + i) * 128 + o) * 384 + tp * 128 + c] =
                f2bf(acc[bb] + bias);
    } else {
        int q = (int)(p - KCONST); int i = q >> 7, o = q & 127;
        #pragma unroll
        for (int bb = 0; bb < 8; ++bb)
            bmean[(bb * 4 + i) * 128 + o] = acc[bb] + bias;
    }
}

// ------ Kernel 3: ALL 4 dilated conv layers fused, signal lives in LDS ------
// v6: same tile per block, but 8 WAVES (512 threads): wave=(wm in 0..3 o-
// quarter, wn in 0..1 t-half) -> acc[2][3]=24 AGPRs, 2 A-loads/ks/wave (v3's
// proven ratio; round-4 showed 4 A-loads/ks is the latency killer), 3 B
// ds_reads/ks/wave (v5's halved count). __launch_bounds__(512,6): ~85 unified
// regs/wave, 3 blocks/CU = 24 waves/CU (2x v3) to hide the L2 A-load latency
// the K-loop is bound by. Per-wave unified estimate 56-72 (v3 measured 80
// incl. 48-AGPR acc; acc now 24). WRITE_SIZE >80 MB = spill tripwire.
// LROW=128 + XOR swizzle of 16B chunks (chunk ^= row&7) at staging,
// writeback, and B-read (verified v4/v5). fp32 residual chain lives in the
// MFMA accumulator (C-in carries x_l, never re-zeroed); acc initialized from
// x while staged lines are cache-hot. All layers compute rows 8..104 =
// [T0-16,T0+80); stale guard rows only corrupt edge outputs discarded by
// validity analysis (valid y3 superset [T0-2,T0+66) superset of [T0,T0+64)).
__global__ __launch_bounds__(512, 6) void k_fused(
    const float* __restrict__ src, float* __restrict__ dst,
    const unsigned short* __restrict__ W, const float* __restrict__ bmean,
    const float* __restrict__ alpha)
{
    __shared__ __align__(16) unsigned short xhi[ROWS * LROW];  // 28672 B

    int tid  = threadIdx.x;
    int lane = tid & 63;
    int wave = tid >> 6;          // 0..7
    int b    = blockIdx.x >> 8;
    int tile = blockIdx.x & 255;
    int T0   = tile * TILE_T;

    int nrow = lane & 15;
    int quad = lane >> 4;
    int wm   = wave & 3;          // o-quarter
    int wn   = wave >> 2;         // t-half
    int o0   = wm * 32;
    int tb   = wn * 48;           // row offset within the 96 computed rows

    const float* xb = src + (long)b * CHN * TT;

    // --- stage x (bf16 hi) into the swizzled LDS image: wave covers its
    //     16-channel slice over all 112 rows; lane->t coalesced global ---
    {
        int cb   = wave * 16;
        int c16b = wave * 2;      // chunk base = cb/8
        #pragma unroll 1
        for (int pass = 0; pass < 2; ++pass) {
            int tl = pass * 64 + lane;
            if (tl < ROWS) {
                int tg = T0 - 24 + tl;
                bool ok = (tg >= 0) && (tg < TT);
                int sw = tl & 7;
                #pragma unroll
                for (int kb = 0; kb < 2; ++kb) {
                    float v[8];
                    #pragma unroll
                    for (int k = 0; k < 8; ++k)
                        v[k] = ok ? xb[(long)(cb + kb * 8 + k) * TT + tg] : 0.f;
                    u16x8 h;
                    #pragma unroll
                    for (int k = 0; k < 8; ++k) h[k] = f2bf(v[k]);
                    *(u16x8*)&xhi[tl * LROW + (((c16b + kb) ^ sw) << 3)] = h;
                }
            }
        }
    }

    // persistent fp32 accumulator = residual chain; init acc = x (cache-hot)
    f32x4 acc[2][3];
    #pragma unroll
    for (int m = 0; m < 2; ++m) {
        int obase = o0 + m * 16 + quad * 4;
        #pragma unroll
        for (int nt = 0; nt < 3; ++nt) {
            int tg = T0 - 16 + tb + nt * 16 + nrow;
            bool ok = ((unsigned)tg < (unsigned)TT);
            #pragma unroll
            for (int r = 0; r < 4; ++r)
                acc[m][nt][r] = ok ? xb[(long)(obase + r) * TT + tg] : 0.f;
        }
    }

    __syncthreads();

    #pragma unroll 1
    for (int l = 0; l < 4; ++l) {
        const int d = 1 << l;
        const unsigned short* Wl = W + (long)((b * 4 + l) * 128) * 384;
        const float* bm = bmean + (b * 4 + l) * 128;

        // bias for this layer (8 regs); loads drain under the K-loop
        float bias[2][4];
        #pragma unroll
        for (int m = 0; m < 2; ++m) {
            int obase = o0 + m * 16 + quad * 4;
            #pragma unroll
            for (int r = 0; r < 4; ++r) bias[m][r] = bm[obase + r];
        }

        // K-loop: 2 transient A-frags per ks + 3 swizzled B ds_reads;
        // MFMA C-in carries x_l (fp32 residual)
        #pragma unroll
        for (int ks = 0; ks < 12; ++ks) {
            int roff = GUARD + tb + nrow + ((ks >> 2) - 1) * d;
            int ch   = (((ks & 3) * 4 + quad) ^ (roff & 7)) << 3;
            const unsigned short* wr =
                Wl + (long)(o0 + nrow) * 384 + ks * 32 + quad * 8;
            bf16x8 a0 = *(const bf16x8*)(wr);
            bf16x8 a1 = *(const bf16x8*)(wr + 16 * 384);
            #pragma unroll
            for (int nt = 0; nt < 3; ++nt) {
                bf16x8 bf =
                    *(const bf16x8*)&xhi[(roff + nt * 16) * LROW + ch];
                acc[0][nt] = __builtin_amdgcn_mfma_f32_16x16x32_bf16(
                    a0, bf, acc[0][nt], 0, 0, 0);
                acc[1][nt] = __builtin_amdgcn_mfma_f32_16x16x32_bf16(
                    a1, bf, acc[1][nt], 0, 0, 0);
            }
        }

        // fold bias into acc (residual already carried in acc)
        #pragma unroll
        for (int m = 0; m < 2; ++m)
            #pragma unroll
            for (int nt = 0; nt < 3; ++nt)
                #pragma unroll
                for (int r = 0; r < 4; ++r)
                    acc[m][nt][r] += bias[m][r];

        __syncthreads();   // all LDS reads of layer l done before any write

        if (l < 3) {
            // write back the bf16 image for layer l+1 (swizzled)
            #pragma unroll
            for (int m = 0; m < 2; ++m) {
                int obase = o0 + m * 16 + quad * 4;
                int ch0 = obase >> 3, sub = obase & 7;
                #pragma unroll
                for (int nt = 0; nt < 3; ++nt) {
                    int trow = GUARD + tb + nt * 16 + nrow;
                    int tg = T0 - 16 + tb + nt * 16 + nrow;
                    bool ok = ((unsigned)tg < (unsigned)TT);
                    u16x4 h;
                    #pragma unroll
                    for (int r = 0; r < 4; ++r) {
                        float v = ok ? acc[m][nt][r] : 0.f;
                        h[r] = f2bf(v);
                    }
                    *(u16x4*)&xhi[trow * LROW +
                                  (((ch0 ^ (trow & 7)) << 3) + sub)] = h;
                }
            }
            __syncthreads();
        } else {
            // final layer: sin activation, store only the valid 64-t core
            #pragma unroll
            for (int m = 0; m < 2; ++m) {
                #pragma unroll
                for (int r = 0; r < 4; ++r) {
                    int o = o0 + m * 16 + quad * 4 + r;
                    float av = alpha[o];
                    float rcp = 1.0f / (av + 1e-8f);
                    long rowoff = ((long)b * CHN + o) * TT + T0;
                    #pragma unroll
                    for (int nt = 0; nt < 3; ++nt) {
                        int trel0 = tb + nt * 16 - 16;
                        if ((unsigned)trel0 < 64u) {   // wave-uniform guard
                            float xn = acc[m][nt][r];
                            float s = __sinf(av * xn);
                            dst[rowoff + trel0 + nrow] = xn + rcp * s * s;
                        }
                    }
                }
            }
        }
    }
}

extern "C" void kernel_launch(void* const* d_in, const int* in_sizes, int n_in,
                              void* d_out, int out_size, void* d_ws, size_t ws_size,
                              hipStream_t stream) {
    const float* x     = (const float*)d_in[0];
    const float* cond  = (const float*)d_in[1];
    const float* w0    = (const float*)d_in[2];
    const float* b0    = (const float*)d_in[3];
    const float* w1    = (const float*)d_in[4];
    const float* b1    = (const float*)d_in[5];
    const float* w2    = (const float*)d_in[6];
    const float* b2    = (const float*)d_in[7];
    const float* alpha = (const float*)d_in[8];
    float* out = (float*)d_out;

    char* ws = (char*)d_ws;
    unsigned short* W = (unsigned short*)ws;               // 3,145,728 B
    float* bmean = (float*)(ws + 3145728);                 // 16,384 B
    float* hbar  = (float*)(ws + 3162112);                 // 2,048 B
    float* h0    = (float*)(ws + 3164160);                 // 65,536 B

    k_cond0<<<64, 256, 0, stream>>>(cond, w0, b0, h0);
    k_cond1<<<64, 256, 0, stream>>>(h0, w1, b1, hbar);
    k_weights<<<772, 256, 0, stream>>>(w2, b2, hbar, W, bmean);
    k_fused<<<2048, 512, 0, stream>>>(x, out, W, bmean, alpha);
}

// Round 6
// 335.145 us; speedup vs baseline: 4.5533x; 1.2273x over previous
//
#include <hip/hip_runtime.h>
#include <math.h>

#define CHN 128
#define TT 16384
#define NBATCH 8
#define KCONST 196608      // 128*128*3*4
#define TILE_T 64
#define GUARD 8
#define CRANGE 96          // computed range per layer: [T0-16, T0+80)
#define ROWS 112           // CRANGE + 2*GUARD, t = T0 - 24 + row
#define LROW 128           // ushorts per LDS row (256 B); 16B chunks XOR-swizzled
#define FRAG 512           // elems per A-frag (64 lanes x 8)
#define KSN 12             // ks steps per layer
#define OTILE_STRIDE (KSN * FRAG)      // 6144 elems per o-tile
#define BL_STRIDE (8 * OTILE_STRIDE)   // 49152 elems per (b,layer)

typedef __bf16 bf16x8 __attribute__((ext_vector_type(8)));
typedef float  f32x4  __attribute__((ext_vector_type(4)));
typedef unsigned short u16x8 __attribute__((ext_vector_type(8)));
typedef unsigned short u16x4 __attribute__((ext_vector_type(4)));

__device__ __forceinline__ unsigned short f2bf(float f) {
    union { float f; unsigned int u; } v; v.f = f;
    unsigned int u = v.u;
    u += 0x7fffu + ((u >> 16) & 1u);   // round-to-nearest-even
    return (unsigned short)(u >> 16);
}
__device__ __forceinline__ float b2f(unsigned short h) {
    union { float f; unsigned int u; } v; v.u = ((unsigned int)h) << 16;
    return v.f;
}

__device__ __forceinline__ float gelu_exact(float x) {
    return 0.5f * x * (1.0f + erff(x * 0.70710678118654752f));
}

// ------------- Kernel 1a: conv0 (80->64, k=5, pad=2) + gelu -> h0 -------------
__global__ __launch_bounds__(256) void k_cond0(
    const float* __restrict__ cond, const float* __restrict__ w0,
    const float* __restrict__ b0, float* __restrict__ h0)
{
    __shared__ float cS[80 * 32];
    __shared__ float wS[8 * 80 * 5];
    __shared__ float bS[8];
    int b = blockIdx.x >> 3, g = blockIdx.x & 7;
    int tid = threadIdx.x;

    for (int idx = tid; idx < 80 * 32; idx += 256) cS[idx] = cond[b * 2560 + idx];
    for (int idx = tid; idx < 8 * 400; idx += 256) wS[idx] = w0[g * 3200 + idx];
    if (tid < 8) bS[tid] = b0[g * 8 + tid];
    __syncthreads();

    int oc = tid >> 5, t = tid & 31;
    float acc = bS[oc];
    const float* wr = wS + oc * 400;
    for (int ic = 0; ic < 80; ++ic) {
        const float* cr = cS + ic * 32;
        #pragma unroll
        for (int j = 0; j < 5; ++j) {
            int tv = t - 2 + j;
            if (tv >= 0 && tv < 32) acc += wr[ic * 5 + j] * cr[tv];
        }
    }
    h0[(b * 64 + g * 8 + oc) * 32 + t] = gelu_exact(acc);
}

// ------ Kernel 1b: conv1 (64->64, k=3, pad=1) + gelu + mean_t -> hbar --------
__global__ __launch_bounds__(256) void k_cond1(
    const float* __restrict__ h0, const float* __restrict__ w1,
    const float* __restrict__ b1, float* __restrict__ hbar)
{
    __shared__ float hS[64 * 32];
    __shared__ float wS[8 * 64 * 3];
    __shared__ float bS[8];
    int b = blockIdx.x >> 3, g = blockIdx.x & 7;
    int tid = threadIdx.x;

    for (int idx = tid; idx < 64 * 32; idx += 256) hS[idx] = h0[b * 2048 + idx];
    for (int idx = tid; idx < 8 * 192; idx += 256) wS[idx] = w1[g * 1536 + idx];
    if (tid < 8) bS[tid] = b1[g * 8 + tid];
    __syncthreads();

    int oc = tid >> 5, t = tid & 31;
    float acc = bS[oc];
    const float* wr = wS + oc * 192;
    for (int ic = 0; ic < 64; ++ic) {
        const float* hr = hS + ic * 32;
        #pragma unroll
        for (int j = 0; j < 3; ++j) {
            int tv = t - 1 + j;
            if (tv >= 0 && tv < 32) acc += wr[ic * 3 + j] * hr[tv];
        }
    }
    float v = gelu_exact(acc);
    #pragma unroll
    for (int off = 1; off < 32; off <<= 1) v += __shfl_xor(v, off, 64);
    if (t == 0) hbar[b * 64 + g * 8 + oc] = v * (1.0f / 32.0f);
}

// ---- Kernel 2: kernels/biases. LDS-staged coalesced w2 reads. ----
// W output layout (v7): frag-contiguous for the MFMA consumer:
//   W[((bl*8 + o>>4)*12 + ks)*512 + quad*128 + (o&15)*8 + (c&7)]
//   where ks = tp*4 + (c>>5), quad = (c>>3)&3.
// One wave's A-frag (16 o-rows x 32 k) is a contiguous 1024 B block with
// lane i at base + i*16 B -- ideal coalescing (8 dense 128 B lines vs the
// old row-strided 16 scattered 64 B segments per load).
__global__ __launch_bounds__(256) void k_weights(
    const float* __restrict__ w2, const float* __restrict__ b2,
    const float* __restrict__ hbar,
    unsigned short* __restrict__ W, float* __restrict__ bmean)
{
    __shared__ float hS[8 * 64];
    __shared__ float buf[256 * 68];   // 256 rows x 64 floats, +4 pad
    int tid = threadIdx.x;
    for (int idx = tid; idx < 512; idx += 256) hS[idx] = hbar[idx];

    // stage this block's 256 w2 rows (64 KB) via coalesced float4 stream
    const float4* src4 = (const float4*)(w2 + (long)blockIdx.x * 16384);
    #pragma unroll
    for (int it = 0; it < 16; ++it) {
        int f = it * 256 + tid;
        float4 v = src4[f];
        int row = f >> 4, col = f & 15;
        *(float4*)&buf[row * 68 + col * 4] = v;
    }
    __syncthreads();

    long p = (long)blockIdx.x * 256 + tid;   // [0, 197632), exact
    const float* rowp = &buf[tid * 68];
    float acc[8];
    #pragma unroll
    for (int bb = 0; bb < 8; ++bb) acc[bb] = 0.f;
    #pragma unroll
    for (int q = 0; q < 16; ++q) {
        float4 wv = *(const float4*)&rowp[q * 4];
        #pragma unroll
        for (int bb = 0; bb < 8; ++bb) {
            const float* h = hS + bb * 64 + q * 4;
            acc[bb] += wv.x * h[0] + wv.y * h[1] + wv.z * h[2] + wv.w * h[3];
        }
    }
    float bias = b2[p];
    if (p < KCONST) {
        int i = (int)(p / 49152); int r = (int)(p % 49152);
        int o = r / 384; int m = r % 384; int c = m / 3; int tp = m % 3;
        int ks = tp * 4 + (c >> 5);
        int within = ((c >> 3) & 3) * 128 + (o & 15) * 8 + (c & 7);
        long fbase = ((long)(o >> 4) * KSN + ks) * FRAG + within;
        #pragma unroll
        for (int bb = 0; bb < 8; ++bb)
            W[(long)(bb * 4 + i) * BL_STRIDE + fbase] = f2bf(acc[bb] + bias);
    } else {
        int q = (int)(p - KCONST); int i = q >> 7, o = q & 127;
        #pragma unroll
        for (int bb = 0; bb < 8; ++bb)
            bmean[(bb * 4 + i) * 128 + o] = acc[bb] + bias;
    }
}

// ------ Kernel 3: ALL 4 dilated conv layers fused, signal lives in LDS ------
// v7 = v5 structure (256 thr, 4 waves 2x2: wave=(wm o-half, wn t-half),
// acc[4][3], halved block LDS B-traffic -- verified conflicts 5.9e6) +
// FRAG-CONTIGUOUS A-loads: each of the 4 per-ks A-loads is now one dense
// 1024 B wave read (lane*16 B) instead of 16 scattered 64 B segments.
// Rounds 4/5 showed the K-loop is L2-transaction-bound on A (4 scattered
// loads/ks vs 12 MFMAs; occupancy alone -- 63% in v6 -- didn't help),
// so transaction count /4 is the single variable this round.
// __launch_bounds__(256,3): ~170-reg unified cap, proven no-spill for the
// ~132-reg working set (v5: VGPR 84 + 48 AGPR acc). WRITE_SIZE > 70 MB =
// spill tripwire. LROW=128 + XOR swizzle of 16B chunks (chunk ^= row&7) at
// staging, writeback, and B-read (verified v4/v5/v6). fp32 residual chain
// lives in the MFMA accumulator (C-in carries x_l, never re-zeroed); acc
// initialized from x while staged lines are cache-hot. All layers compute
// rows 8..104 = [T0-16,T0+80); stale guard rows only corrupt edge outputs
// discarded by validity analysis (valid y3 sup [T0-2,T0+66) sup [T0,T0+64)).
__global__ __launch_bounds__(256, 3) void k_fused(
    const float* __restrict__ src, float* __restrict__ dst,
    const unsigned short* __restrict__ W, const float* __restrict__ bmean,
    const float* __restrict__ alpha)
{
    __shared__ __align__(16) unsigned short xhi[ROWS * LROW];  // 28672 B

    int tid  = threadIdx.x;
    int lane = tid & 63;
    int wave = tid >> 6;
    int b    = blockIdx.x >> 8;
    int tile = blockIdx.x & 255;
    int T0   = tile * TILE_T;

    int nrow = lane & 15;
    int quad = lane >> 4;
    int wm   = wave & 1;          // o-half
    int wn   = wave >> 1;         // t-half
    int o0   = wm * 64;
    int tb   = wn * 48;           // row offset within the 96 computed rows

    const float* xb = src + (long)b * CHN * TT;

    // --- stage x (bf16 hi) into the swizzled LDS image ---
    {
        int cb   = wave * 32;
        int c16b = wave * 4;      // chunk base = cb/8
        #pragma unroll 1
        for (int pass = 0; pass < 2; ++pass) {
            int tl = pass * 64 + lane;
            if (tl < ROWS) {
                int tg = T0 - 24 + tl;
                bool ok = (tg >= 0) && (tg < TT);
                int sw = tl & 7;
                #pragma unroll
                for (int kb = 0; kb < 4; ++kb) {
                    float v[8];
                    #pragma unroll
                    for (int k = 0; k < 8; ++k)
                        v[k] = ok ? xb[(long)(cb + kb * 8 + k) * TT + tg] : 0.f;
                    u16x8 h;
                    #pragma unroll
                    for (int k = 0; k < 8; ++k) h[k] = f2bf(v[k]);
                    *(u16x8*)&xhi[tl * LROW + (((c16b + kb) ^ sw) << 3)] = h;
                }
            }
        }
    }

    // persistent fp32 accumulator = residual chain; init acc = x (cache-hot)
    f32x4 acc[4][3];
    #pragma unroll
    for (int m = 0; m < 4; ++m) {
        int obase = o0 + m * 16 + quad * 4;
        #pragma unroll
        for (int nt = 0; nt < 3; ++nt) {
            int tg = T0 - 16 + tb + nt * 16 + nrow;
            bool ok = ((unsigned)tg < (unsigned)TT);
            #pragma unroll
            for (int r = 0; r < 4; ++r)
                acc[m][nt][r] = ok ? xb[(long)(obase + r) * TT + tg] : 0.f;
        }
    }

    __syncthreads();

    #pragma unroll 1
    for (int l = 0; l < 4; ++l) {
        const int d = 1 << l;
        // frag-contiguous W: this wave's 4 o-tiles start at (wm*4 + m)
        const unsigned short* Wl =
            W + (long)(b * 4 + l) * BL_STRIDE + (long)(wm * 4) * OTILE_STRIDE
              + lane * 8;
        const float* bm = bmean + (b * 4 + l) * 128;

        // bias for this layer (16 regs); loads drain under the K-loop
        float bias[4][4];
        #pragma unroll
        for (int m = 0; m < 4; ++m) {
            int obase = o0 + m * 16 + quad * 4;
            #pragma unroll
            for (int r = 0; r < 4; ++r) bias[m][r] = bm[obase + r];
        }

        // K-loop: 4 dense 1024 B A-loads per ks + 3 swizzled B ds_reads;
        // B-frag feeds 4 m-tiles; MFMA C-in carries x_l (fp32 residual)
        #pragma unroll
        for (int ks = 0; ks < 12; ++ks) {
            int roff = GUARD + tb + nrow + ((ks >> 2) - 1) * d;
            int ch   = (((ks & 3) * 4 + quad) ^ (roff & 7)) << 3;
            const unsigned short* wr = Wl + ks * FRAG;
            bf16x8 a0 = *(const bf16x8*)(wr);
            bf16x8 a1 = *(const bf16x8*)(wr + OTILE_STRIDE);
            bf16x8 a2 = *(const bf16x8*)(wr + 2 * OTILE_STRIDE);
            bf16x8 a3 = *(const bf16x8*)(wr + 3 * OTILE_STRIDE);
            #pragma unroll
            for (int nt = 0; nt < 3; ++nt) {
                bf16x8 bf =
                    *(const bf16x8*)&xhi[(roff + nt * 16) * LROW + ch];
                acc[0][nt] = __builtin_amdgcn_mfma_f32_16x16x32_bf16(
                    a0, bf, acc[0][nt], 0, 0, 0);
                acc[1][nt] = __builtin_amdgcn_mfma_f32_16x16x32_bf16(
                    a1, bf, acc[1][nt], 0, 0, 0);
                acc[2][nt] = __builtin_amdgcn_mfma_f32_16x16x32_bf16(
                    a2, bf, acc[2][nt], 0, 0, 0);
                acc[3][nt] = __builtin_amdgcn_mfma_f32_16x16x32_bf16(
                    a3, bf, acc[3][nt], 0, 0, 0);
            }
        }

        // fold bias into acc (residual already carried in acc)
        #pragma unroll
        for (int m = 0; m < 4; ++m)
            #pragma unroll
            for (int nt = 0; nt < 3; ++nt)
                #pragma unroll
                for (int r = 0; r < 4; ++r)
                    acc[m][nt][r] += bias[m][r];

        __syncthreads();   // all LDS reads of layer l done before any write

        if (l < 3) {
            // write back the bf16 image for layer l+1 (swizzled)
            #pragma unroll
            for (int m = 0; m < 4; ++m) {
                int obase = o0 + m * 16 + quad * 4;
                int ch0 = obase >> 3, sub = obase & 7;
                #pragma unroll
                for (int nt = 0; nt < 3; ++nt) {
                    int trow = GUARD + tb + nt * 16 + nrow;
                    int tg = T0 - 16 + tb + nt * 16 + nrow;
                    bool ok = ((unsigned)tg < (unsigned)TT);
                    u16x4 h;
                    #pragma unroll
                    for (int r = 0; r < 4; ++r) {
                        float v = ok ? acc[m][nt][r] : 0.f;
                        h[r] = f2bf(v);
                    }
                    *(u16x4*)&xhi[trow * LROW +
                                  (((ch0 ^ (trow & 7)) << 3) + sub)] = h;
                }
            }
            __syncthreads();
        } else {
            // final layer: sin activation, store only the valid 64-t core
            #pragma unroll
            for (int m = 0; m < 4; ++m) {
                #pragma unroll
                for (int r = 0; r < 4; ++r) {
                    int o = o0 + m * 16 + quad * 4 + r;
                    float av = alpha[o];
                    float rcp = 1.0f / (av + 1e-8f);
                    long rowoff = ((long)b * CHN + o) * TT + T0;
                    #pragma unroll
                    for (int nt = 0; nt < 3; ++nt) {
                        int trel0 = tb + nt * 16 - 16;
                        if ((unsigned)trel0 < 64u) {   // wave-uniform guard
                            float xn = acc[m][nt][r];
                            float s = __sinf(av * xn);
                            dst[rowoff + trel0 + nrow] = xn + rcp * s * s;
                        }
                    }
                }
            }
        }
    }
}

extern "C" void kernel_launch(void* const* d_in, const int* in_sizes, int n_in,
                              void* d_out, int out_size, void* d_ws, size_t ws_size,
                              hipStream_t stream) {
    const float* x     = (const float*)d_in[0];
    const float* cond  = (const float*)d_in[1];
    const float* w0    = (const float*)d_in[2];
    const float* b0    = (const float*)d_in[3];
    const float* w1    = (const float*)d_in[4];
    const float* b1    = (const float*)d_in[5];
    const float* w2    = (const float*)d_in[6];
    const float* b2    = (const float*)d_in[7];
    const float* alpha = (const float*)d_in[8];
    float* out = (float*)d_out;

    char* ws = (char*)d_ws;
    unsigned short* W = (unsigned short*)ws;               // 3,145,728 B
    float* bmean = (float*)(ws + 3145728);                 // 16,384 B
    float* hbar  = (float*)(ws + 3162112);                 // 2,048 B
    float* h0    = (float*)(ws + 3164160);                 // 65,536 B

    k_cond0<<<64, 256, 0, stream>>>(cond, w0, b0, h0);
    k_cond1<<<64, 256, 0, stream>>>(h0, w1, b1, hbar);
    k_weights<<<772, 256, 0, stream>>>(w2, b2, hbar, W, bmean);
    k_fused<<<2048, 256, 0, stream>>>(x, out, W, bmean, alpha);
}

// Round 7
// 298.936 us; speedup vs baseline: 5.1048x; 1.1211x over previous
//
#include <hip/hip_runtime.h>
#include <math.h>

#define CHN 128
#define TT 16384
#define NBATCH 8
#define KCONST 196608      // 128*128*3*4
#define TILE_T 64
#define GUARD 8
#define CRANGE 96          // computed range per layer: [T0-16, T0+80)
#define ROWS 112           // CRANGE + 2*GUARD, t = T0 - 24 + row
#define LROW 128           // ushorts per LDS row (256 B); 16B chunks XOR-swizzled
#define FRAG 512           // elems per A-frag (64 lanes x 8)
#define KSN 12             // ks steps per layer
#define OTILE_STRIDE (KSN * FRAG)      // 6144 elems per o-tile
#define BL_STRIDE (8 * OTILE_STRIDE)   // 49152 elems per (b,layer)

typedef __bf16 bf16x8 __attribute__((ext_vector_type(8)));
typedef float  f32x4  __attribute__((ext_vector_type(4)));
typedef unsigned short u16x8 __attribute__((ext_vector_type(8)));
typedef unsigned short u16x4 __attribute__((ext_vector_type(4)));

__device__ __forceinline__ unsigned short f2bf(float f) {
    union { float f; unsigned int u; } v; v.f = f;
    unsigned int u = v.u;
    u += 0x7fffu + ((u >> 16) & 1u);   // round-to-nearest-even
    return (unsigned short)(u >> 16);
}
__device__ __forceinline__ float b2f(unsigned short h) {
    union { float f; unsigned int u; } v; v.u = ((unsigned int)h) << 16;
    return v.f;
}

__device__ __forceinline__ float gelu_exact(float x) {
    return 0.5f * x * (1.0f + erff(x * 0.70710678118654752f));
}

// ------------- Kernel 1a: conv0 (80->64, k=5, pad=2) + gelu -> h0 -------------
__global__ __launch_bounds__(256) void k_cond0(
    const float* __restrict__ cond, const float* __restrict__ w0,
    const float* __restrict__ b0, float* __restrict__ h0)
{
    __shared__ float cS[80 * 32];
    __shared__ float wS[8 * 80 * 5];
    __shared__ float bS[8];
    int b = blockIdx.x >> 3, g = blockIdx.x & 7;
    int tid = threadIdx.x;

    for (int idx = tid; idx < 80 * 32; idx += 256) cS[idx] = cond[b * 2560 + idx];
    for (int idx = tid; idx < 8 * 400; idx += 256) wS[idx] = w0[g * 3200 + idx];
    if (tid < 8) bS[tid] = b0[g * 8 + tid];
    __syncthreads();

    int oc = tid >> 5, t = tid & 31;
    float acc = bS[oc];
    const float* wr = wS + oc * 400;
    for (int ic = 0; ic < 80; ++ic) {
        const float* cr = cS + ic * 32;
        #pragma unroll
        for (int j = 0; j < 5; ++j) {
            int tv = t - 2 + j;
            if (tv >= 0 && tv < 32) acc += wr[ic * 5 + j] * cr[tv];
        }
    }
    h0[(b * 64 + g * 8 + oc) * 32 + t] = gelu_exact(acc);
}

// ------ Kernel 1b: conv1 (64->64, k=3, pad=1) + gelu + mean_t -> hbar --------
__global__ __launch_bounds__(256) void k_cond1(
    const float* __restrict__ h0, const float* __restrict__ w1,
    const float* __restrict__ b1, float* __restrict__ hbar)
{
    __shared__ float hS[64 * 32];
    __shared__ float wS[8 * 64 * 3];
    __shared__ float bS[8];
    int b = blockIdx.x >> 3, g = blockIdx.x & 7;
    int tid = threadIdx.x;

    for (int idx = tid; idx < 64 * 32; idx += 256) hS[idx] = h0[b * 2048 + idx];
    for (int idx = tid; idx < 8 * 192; idx += 256) wS[idx] = w1[g * 1536 + idx];
    if (tid < 8) bS[tid] = b1[g * 8 + tid];
    __syncthreads();

    int oc = tid >> 5, t = tid & 31;
    float acc = bS[oc];
    const float* wr = wS + oc * 192;
    for (int ic = 0; ic < 64; ++ic) {
        const float* hr = hS + ic * 32;
        #pragma unroll
        for (int j = 0; j < 3; ++j) {
            int tv = t - 1 + j;
            if (tv >= 0 && tv < 32) acc += wr[ic * 3 + j] * hr[tv];
        }
    }
    float v = gelu_exact(acc);
    #pragma unroll
    for (int off = 1; off < 32; off <<= 1) v += __shfl_xor(v, off, 64);
    if (t == 0) hbar[b * 64 + g * 8 + oc] = v * (1.0f / 32.0f);
}

// ---- Kernel 2: kernels/biases. LDS-staged coalesced w2 reads. ----
// W output layout (v7, verified): frag-contiguous for the MFMA consumer:
//   W[((bl*8 + o>>4)*12 + ks)*512 + quad*128 + (o&15)*8 + (c&7)]
//   where ks = tp*4 + (c>>5), quad = (c>>3)&3.
// One wave's A-frag (16 o-rows x 32 k) is a contiguous 1024 B block with
// lane i at base + i*16 B -- ideal coalescing (round 6: 258->162 us).
__global__ __launch_bounds__(256) void k_weights(
    const float* __restrict__ w2, const float* __restrict__ b2,
    const float* __restrict__ hbar,
    unsigned short* __restrict__ W, float* __restrict__ bmean)
{
    __shared__ float hS[8 * 64];
    __shared__ float buf[256 * 68];   // 256 rows x 64 floats, +4 pad
    int tid = threadIdx.x;
    for (int idx = tid; idx < 512; idx += 256) hS[idx] = hbar[idx];

    // stage this block's 256 w2 rows (64 KB) via coalesced float4 stream
    const float4* src4 = (const float4*)(w2 + (long)blockIdx.x * 16384);
    #pragma unroll
    for (int it = 0; it < 16; ++it) {
        int f = it * 256 + tid;
        float4 v = src4[f];
        int row = f >> 4, col = f & 15;
        *(float4*)&buf[row * 68 + col * 4] = v;
    }
    __syncthreads();

    long p = (long)blockIdx.x * 256 + tid;   // [0, 197632), exact
    const float* rowp = &buf[tid * 68];
    float acc[8];
    #pragma unroll
    for (int bb = 0; bb < 8; ++bb) acc[bb] = 0.f;
    #pragma unroll
    for (int q = 0; q < 16; ++q) {
        float4 wv = *(const float4*)&rowp[q * 4];
        #pragma unroll
        for (int bb = 0; bb < 8; ++bb) {
            const float* h = hS + bb * 64 + q * 4;
            acc[bb] += wv.x * h[0] + wv.y * h[1] + wv.z * h[2] + wv.w * h[3];
        }
    }
    float bias = b2[p];
    if (p < KCONST) {
        int i = (int)(p / 49152); int r = (int)(p % 49152);
        int o = r / 384; int m = r % 384; int c = m / 3; int tp = m % 3;
        int ks = tp * 4 + (c >> 5);
        int within = ((c >> 3) & 3) * 128 + (o & 15) * 8 + (c & 7);
        long fbase = ((long)(o >> 4) * KSN + ks) * FRAG + within;
        #pragma unroll
        for (int bb = 0; bb < 8; ++bb)
            W[(long)(bb * 4 + i) * BL_STRIDE + fbase] = f2bf(acc[bb] + bias);
    } else {
        int q = (int)(p - KCONST); int i = q >> 7, o = q & 127;
        #pragma unroll
        for (int bb = 0; bb < 8; ++bb)
            bmean[(bb * 4 + i) * 128 + o] = acc[bb] + bias;
    }
}

// ------ Kernel 3: ALL 4 dilated conv layers fused, signal lives in LDS ------
// v8: 8 WAVES (512 thr), wave=(wm in 0..3 o-quarter, wn in 0..1 t-half),
// acc[2][3]=24 AGPR; frag-contiguous A (verified round 6). Working set
// ~75-90 unified regs fits __launch_bounds__(512,4)'s 128 cap WITH slack
// (v6's spill was the 85 cap at (512,6)) -> 2 blocks/CU = 16 waves/CU.
// DOUBLE-BUFFERED LDS (2 x 28672 B): layer l reads buf[l&1], writes
// buf[(l+1)&1] -> ONE barrier per layer (4 total, was 7); writeback overlaps
// lagging waves' K-loop reads. buf1 guard rows (0-7, 104-111; never written
// by writebacks which cover rows 8..103) are zeroed at staging so all reads
// are finite; contaminated edge outputs stay outside stored rows 24..88
// (validity margin 8*d shrink per layer, worst-case rows 8..21 / 91..104).
// buf0 guard rows keep original x (finite). fp32 residual chain lives in the
// MFMA accumulator (C-in carries x_l, never re-zeroed); acc initialized from
// x while staged lines are cache-hot. Bias loaded AFTER the K-loop (live-
// range hygiene; round-6's 56 MB scratch = hoisting overflow at cap 170).
// WRITE_SIZE > 70 MB = spill tripwire.
__global__ __launch_bounds__(512, 4) void k_fused(
    const float* __restrict__ src, float* __restrict__ dst,
    const unsigned short* __restrict__ W, const float* __restrict__ bmean,
    const float* __restrict__ alpha)
{
    __shared__ __align__(16) unsigned short xs[2][ROWS * LROW];  // 57344 B

    int tid  = threadIdx.x;
    int lane = tid & 63;
    int wave = tid >> 6;          // 0..7
    int b    = blockIdx.x >> 8;
    int tile = blockIdx.x & 255;
    int T0   = tile * TILE_T;

    int nrow = lane & 15;
    int quad = lane >> 4;
    int wm   = wave & 3;          // o-quarter (32 ch)
    int wn   = wave >> 2;         // t-half (48 rows)
    int o0   = wm * 32;
    int tb   = wn * 48;           // row offset within the 96 computed rows

    const float* xb = src + (long)b * CHN * TT;

    // zero buf1's guard rows (rows 0..7 and 104..111; 4 KB) -- these are
    // never written by layer writebacks (rows 8..103) but ARE read by the
    // K-loop's dilated taps; zeros keep everything finite.
    if (tid < 256) {
        int gi  = tid >> 4;                    // 0..15
        int row = (gi < 8) ? gi : gi + 96;     // 0..7, 104..111
        u16x8 z = {0, 0, 0, 0, 0, 0, 0, 0};
        *(u16x8*)&xs[1][row * LROW + (tid & 15) * 8] = z;
    }

    // --- stage x (bf16) into swizzled buf0: wave (wm,wn) covers channels
    //     [wm*32,+32) x rows [wn*64, wn*64+64) (wn=1: 48 rows, lanes>=48 idle)
    {
        int cb   = wm * 32;
        int c16b = wm * 4;        // chunk base = cb/8
        int tl   = wn * 64 + lane;
        if (tl < ROWS) {
            int tg = T0 - 24 + tl;
            bool ok = (tg >= 0) && (tg < TT);
            int sw = tl & 7;
            #pragma unroll
            for (int kb = 0; kb < 4; ++kb) {
                float v[8];
                #pragma unroll
                for (int k = 0; k < 8; ++k)
                    v[k] = ok ? xb[(long)(cb + kb * 8 + k) * TT + tg] : 0.f;
                u16x8 h;
                #pragma unroll
                for (int k = 0; k < 8; ++k) h[k] = f2bf(v[k]);
                *(u16x8*)&xs[0][tl * LROW + (((c16b + kb) ^ sw) << 3)] = h;
            }
        }
    }

    // persistent fp32 accumulator = residual chain; init acc = x (cache-hot)
    f32x4 acc[2][3];
    #pragma unroll
    for (int m = 0; m < 2; ++m) {
        int obase = o0 + m * 16 + quad * 4;
        #pragma unroll
        for (int nt = 0; nt < 3; ++nt) {
            int tg = T0 - 16 + tb + nt * 16 + nrow;
            bool ok = ((unsigned)tg < (unsigned)TT);
            #pragma unroll
            for (int r = 0; r < 4; ++r)
                acc[m][nt][r] = ok ? xb[(long)(obase + r) * TT + tg] : 0.f;
        }
    }

    __syncthreads();

    #pragma unroll 1
    for (int l = 0; l < 4; ++l) {
        const int d = 1 << l;
        const unsigned short* rd = xs[l & 1];
        unsigned short* wbuf = xs[(l + 1) & 1];
        // frag-contiguous W: this wave's 2 o-tiles are (wm*2, wm*2+1)
        const unsigned short* Wl =
            W + (long)(b * 4 + l) * BL_STRIDE + (long)(wm * 2) * OTILE_STRIDE
              + lane * 8;

        // K-loop: 2 dense 1024 B A-loads per ks + 3 swizzled B ds_reads;
        // B-frag feeds 2 m-tiles; MFMA C-in carries x_l (fp32 residual)
        #pragma unroll
        for (int ks = 0; ks < 12; ++ks) {
            int roff = GUARD + tb + nrow + ((ks >> 2) - 1) * d;
            int ch   = (((ks & 3) * 4 + quad) ^ (roff & 7)) << 3;
            const unsigned short* wr = Wl + ks * FRAG;
            bf16x8 a0 = *(const bf16x8*)(wr);
            bf16x8 a1 = *(const bf16x8*)(wr + OTILE_STRIDE);
            #pragma unroll
            for (int nt = 0; nt < 3; ++nt) {
                bf16x8 bf =
                    *(const bf16x8*)&rd[(roff + nt * 16) * LROW + ch];
                acc[0][nt] = __builtin_amdgcn_mfma_f32_16x16x32_bf16(
                    a0, bf, acc[0][nt], 0, 0, 0);
                acc[1][nt] = __builtin_amdgcn_mfma_f32_16x16x32_bf16(
                    a1, bf, acc[1][nt], 0, 0, 0);
            }
        }

        // bias loaded AFTER the K-loop (small, L2-hot) and folded into acc
        {
            const float* bm = bmean + (b * 4 + l) * 128;
            #pragma unroll
            for (int m = 0; m < 2; ++m) {
                int obase = o0 + m * 16 + quad * 4;
                #pragma unroll
                for (int r = 0; r < 4; ++r) {
                    float bv = bm[obase + r];
                    #pragma unroll
                    for (int nt = 0; nt < 3; ++nt)
                        acc[m][nt][r] += bv;
                }
            }
        }

        if (l < 3) {
            // write back the bf16 image for layer l+1 into the OTHER buffer
            // (no barrier needed before: all reads of wbuf finished in layer
            // l-1's K-loop, fenced by the barrier at the end of layer l-1)
            #pragma unroll
            for (int m = 0; m < 2; ++m) {
                int obase = o0 + m * 16 + quad * 4;
                int ch0 = obase >> 3, sub = obase & 7;
                #pragma unroll
                for (int nt = 0; nt < 3; ++nt) {
                    int trow = GUARD + tb + nt * 16 + nrow;
                    int tg = T0 - 16 + tb + nt * 16 + nrow;
                    bool ok = ((unsigned)tg < (unsigned)TT);
                    u16x4 h;
                    #pragma unroll
                    for (int r = 0; r < 4; ++r) {
                        float v = ok ? acc[m][nt][r] : 0.f;
                        h[r] = f2bf(v);
                    }
                    *(u16x4*)&wbuf[trow * LROW +
                                   (((ch0 ^ (trow & 7)) << 3) + sub)] = h;
                }
            }
            __syncthreads();   // writeback visible -> next layer may read
        } else {
            // final layer: sin activation, store only the valid 64-t core
            #pragma unroll
            for (int m = 0; m < 2; ++m) {
                #pragma unroll
                for (int r = 0; r < 4; ++r) {
                    int o = o0 + m * 16 + quad * 4 + r;
                    float av = alpha[o];
                    float rcp = 1.0f / (av + 1e-8f);
                    long rowoff = ((long)b * CHN + o) * TT + T0;
                    #pragma unroll
                    for (int nt = 0; nt < 3; ++nt) {
                        int trel0 = tb + nt * 16 - 16;
                        if ((unsigned)trel0 < 64u) {   // wave-uniform guard
                            float xn = acc[m][nt][r];
                            float s = __sinf(av * xn);
                            dst[rowoff + trel0 + nrow] = xn + rcp * s * s;
                        }
                    }
                }
            }
        }
    }
}

extern "C" void kernel_launch(void* const* d_in, const int* in_sizes, int n_in,
                              void* d_out, int out_size, void* d_ws, size_t ws_size,
                              hipStream_t stream) {
    const float* x     = (const float*)d_in[0];
    const float* cond  = (const float*)d_in[1];
    const float* w0    = (const float*)d_in[2];
    const float* b0    = (const float*)d_in[3];
    const float* w1    = (const float*)d_in[4];
    const float* b1    = (const float*)d_in[5];
    const float* w2    = (const float*)d_in[6];
    const float* b2    = (const float*)d_in[7];
    const float* alpha = (const float*)d_in[8];
    float* out = (float*)d_out;

    char* ws = (char*)d_ws;
    unsigned short* W = (unsigned short*)ws;               // 3,145,728 B
    float* bmean = (float*)(ws + 3145728);                 // 16,384 B
    float* hbar  = (float*)(ws + 3162112);                 // 2,048 B
    float* h0    = (float*)(ws + 3164160);                 // 65,536 B

    k_cond0<<<64, 256, 0, stream>>>(cond, w0, b0, h0);
    k_cond1<<<64, 256, 0, stream>>>(h0, w1, b1, hbar);
    k_weights<<<772, 256, 0, stream>>>(w2, b2, hbar, W, bmean);
    k_fused<<<2048, 512, 0, stream>>>(x, out, W, bmean, alpha);
}